// Round 11
// baseline (136.610 us; speedup 1.0000x reference)
//
#include <hip/hip_runtime.h>

typedef unsigned short u16;
typedef unsigned int u32;
typedef __attribute__((ext_vector_type(8))) short bf16x8;
typedef __attribute__((ext_vector_type(4))) float f32x4;

__device__ __forceinline__ u16 f2bf(float x) {
  union { float f; u32 u; } un; un.f = x;
  u32 r = un.u + 0x7FFFu + ((un.u >> 16) & 1u);
  return (u16)(r >> 16);
}
__device__ __forceinline__ u32 pk2(float a, float b) {
  return (u32)f2bf(a) | ((u32)f2bf(b) << 16);
}

// async global->LDS, 16B per lane; LDS dest must be wave-uniform base + lane*16
__device__ __forceinline__ void gl_lds16(const u16* gsrc, u16* ldst) {
  __builtin_amdgcn_global_load_lds(
      (const __attribute__((address_space(1))) void*)gsrc,
      (__attribute__((address_space(3))) void*)ldst,
      16, 0, 0);
}

// ---------------- prep: weights->bf16, BN fold, bias gather ----------------
// Q's stored scale/shift absorb: its own BN, SCALE=0.25, and K's BN scale sk_c
// (K is stored RAW; K's BN shift contributes only a per-q softmax-invariant const).
__global__ __launch_bounds__(256) void prep_misc(
    const float* __restrict__ Wkv, const float* __restrict__ Wq, const float* __restrict__ Wp,
    const float* __restrict__ gkv, const float* __restrict__ bkv, const float* __restrict__ mkv, const float* __restrict__ vkv,
    const float* __restrict__ gq, const float* __restrict__ bq, const float* __restrict__ mq, const float* __restrict__ vq,
    const float* __restrict__ gp, const float* __restrict__ bp, const float* __restrict__ mp, const float* __restrict__ vp,
    const float* __restrict__ ab, const int* __restrict__ bidx,
    u16* __restrict__ wkvb, u16* __restrict__ wqb, u16* __restrict__ wpb,
    float* __restrict__ skv, float* __restrict__ tkv,
    float* __restrict__ sq, float* __restrict__ tq,
    float* __restrict__ sp, float* __restrict__ tp,
    float* __restrict__ biasf)
{
  int i = blockIdx.x * 256 + threadIdx.x;
  if (i < 327680) { wkvb[i] = f2bf(Wkv[i]); return; }
  i -= 327680;
  if (i < 65536) { wqb[i] = f2bf(Wq[i]); return; }
  i -= 65536;
  if (i < 524288) { wpb[i] = f2bf(Wp[i]); return; }
  i -= 524288;
  if (i < 153664) { biasf[i] = ab[(i / 9604) * 196 + bidx[i % 9604]]; return; }
  i -= 153664;
  if (i < 1280) { float s = gkv[i] * rsqrtf(vkv[i] + 1e-5f); skv[i] = s; tkv[i] = bkv[i] - mkv[i] * s; return; }
  i -= 1280;
  if (i < 256) {
    int h = i >> 4, c = i & 15;
    float sk = gkv[h * 80 + c] * rsqrtf(vkv[h * 80 + c] + 1e-5f);
    float s = gq[i] * rsqrtf(vq[i] + 1e-5f);
    sq[i] = s * 0.25f * sk;
    tq[i] = (bq[i] - mq[i] * s) * 0.25f * sk;
    return;
  }
  i -= 256;
  if (i < 512) { float s = gp[i] * rsqrtf(vp[i] + 1e-5f); sp[i] = s; tp[i] = bp[i] - mp[i] * s; return; }
}

// ---------------- x (f32) -> bf16 ----------------
__global__ __launch_bounds__(256) void conv_x(const float* __restrict__ x, u16* __restrict__ xb)
{
  int u = blockIdx.x * 256 + threadIdx.x;
  float4 v = ((const float4*)x)[u];
  uint2 o;
  o.x = (u32)f2bf(v.x) | ((u32)f2bf(v.y) << 16);
  o.y = (u32)f2bf(v.z) | ((u32)f2bf(v.w) << 16);
  ((uint2*)xb)[u] = o;
}

// ---------------- p-proj GEMM: out = BN(A @ W^T), f32 row-major out ----------------
__global__ __launch_bounds__(256) void gemm_bn(
    const u16* __restrict__ A, const u16* __restrict__ W,
    const float* __restrict__ sv, const float* __restrict__ tv,
    float* __restrict__ outp, int N, int K, int NBLK)
{
  __shared__ u16 As[128 * 64];
  __shared__ u16 Bs[128 * 64];
  const int tid = threadIdx.x;
  const int lane = tid & 63;
  const int wv = tid >> 6, wr = wv >> 1, wc = wv & 1;
  const int lo = lane & 15, hi = lane >> 4;

  int bid = blockIdx.x;
  int cpx = gridDim.x >> 3;
  int wg = (bid & 7) * cpx + (bid >> 3);
  const int m0 = (wg / NBLK) * 128, n0 = (wg % NBLK) * 128;

  f32x4 zero4 = {0.f, 0.f, 0.f, 0.f};
  f32x4 acc[4][4];
#pragma unroll
  for (int m = 0; m < 4; ++m)
#pragma unroll
    for (int n = 0; n < 4; ++n) acc[m][n] = zero4;

  for (int kt = 0; kt < K; kt += 64) {
    __syncthreads();
#pragma unroll
    for (int i = 0; i < 4; ++i) {
      int e = (i * 256 + tid) * 8;
      int r = e >> 6, c = e & 63;
      int cs = c ^ ((r & 7) << 3);
      gl_lds16(A + (long)(m0 + r) * K + (kt + cs), As + e);
      gl_lds16(W + (long)(n0 + r) * K + (kt + cs), Bs + e);
    }
    __syncthreads();
#pragma unroll
    for (int kk = 0; kk < 64; kk += 32) {
      bf16x8 af[4], bfr[4];
#pragma unroll
      for (int m = 0; m < 4; ++m)
        af[m] = *(const bf16x8*)(As + (wr * 64 + m * 16 + lo) * 64 + ((kk + hi * 8) ^ ((lo & 7) << 3)));
#pragma unroll
      for (int n = 0; n < 4; ++n)
        bfr[n] = *(const bf16x8*)(Bs + (wc * 64 + n * 16 + lo) * 64 + ((kk + hi * 8) ^ ((lo & 7) << 3)));
#pragma unroll
      for (int m = 0; m < 4; ++m)
#pragma unroll
        for (int n = 0; n < 4; ++n)
          acc[m][n] = __builtin_amdgcn_mfma_f32_16x16x32_bf16(af[m], bfr[n], acc[m][n], 0, 0, 0);
    }
  }
#pragma unroll
  for (int m = 0; m < 4; ++m) {
    const int row0 = m0 + wr * 64 + m * 16 + hi * 4;
#pragma unroll
    for (int n = 0; n < 4; ++n) {
      const int col = n0 + wc * 64 + n * 16 + lo;
      const float s = sv[col], t = tv[col];
#pragma unroll
      for (int j = 0; j < 4; ++j)
        outp[(long)(row0 + j) * N + col] = acc[m][n][j] * s + t;
    }
  }
}

// ---------------- fused kv-proj + q-proj + attention, one block per (b,h) ----------------
// r6 structure + SPLIT-PV: P lives in a HALF buffer (64x112) and PV runs in two
// key-passes (0..111, 112..207), second half of P retained in sc[] registers
// between passes. LDS peak drops 53,248 -> 40,960 B => 4 blocks/CU.
// LDS map (u16 offsets), regions alias across barrier-separated phases:
//   phase1 staging: x_s [0..13312) 208x64, W_s [13312..19456) 96x64
//   post-GEMM:      vT  [0..13312) 64x208 RAW V, K_s [13312..18304) 208x24 RAW K,
//                   Q_s [18304..19840) 64x24 (BN+folds)
//   post-QK^T:      P_half [13312..20480) 64x112 (aliases K_s/Q_s)
// Total 20480 u16 = 40960 B -> 4 blocks/CU (160KB exactly).
#define VTS   208
#define KOFF  13312
#define KS    24
#define QOFF  18304
#define QS    24
#define PHOFF 13312
#define PHS   112
#define SMEM_N 20480

// range-safe XOR swizzle for stride-208 tiles (vT): permutes within 64-col
// blocks, identity on the 16-wide tail (cols 192..207).
__device__ __forceinline__ int swz(int col, int rowkey) {
  return (col < 192) ? (col ^ ((rowkey & 7) << 3)) : col;
}
// P-half swizzle (stride 112): rows sharing a bank-base differ by 4 ->
// key from (row>>2)&3; identity on tail cols 96..111.
__device__ __forceinline__ int pswz(int col, int row) {
  return (col < 96) ? (col ^ (((row >> 2) & 3) << 3)) : col;
}

__global__ __launch_bounds__(256, 4) void fused_attn(
    const u16* __restrict__ xb, const u16* __restrict__ wkvb, const u16* __restrict__ wqb,
    const float* __restrict__ skv, const float* __restrict__ tkv,
    const float* __restrict__ sqv, const float* __restrict__ tqv,
    const float* __restrict__ biasf, u16* __restrict__ osw)
{
  __shared__ __align__(16) u16 sm[SMEM_N];
  const int tid = threadIdx.x;
  const int bid = blockIdx.x;
  const int wg = (bid & 7) * 512 + (bid >> 3);   // XCD chunk: 32 images per XCD
  const int bb = wg >> 4, hh = wg & 15;
  const int w = tid >> 6, lane = tid & 63, lo = lane & 15, hi = lane >> 4;

  const u16* xbase = xb + (long)bb * 196 * 256;
  const u16* wkvh = wkvb + (long)hh * 80 * 256;
  const u16* wqh  = wqb + (long)hh * 16 * 256;

  f32x4 z4 = {0.f, 0.f, 0.f, 0.f};
  // frags {w, w+4, w+8} x 5 nf; frag 12 split: w1 -> nf0,1; w2 -> nf2,3; w3 -> nf4
  f32x4 acc[3][5];
#pragma unroll
  for (int u = 0; u < 3; ++u)
#pragma unroll
    for (int nf = 0; nf < 5; ++nf) acc[u][nf] = z4;
  f32x4 acc12a = z4, acc12b = z4;
  f32x4 qacc = z4;

  // q A-frag gather row (::2 spatial subsample), clamped; in-tile LDS gather
  int qi = w * 16 + lo; if (qi > 48) qi = 48;
  const int gr = (qi / 7) * 28 + (qi % 7) * 2;

  // ---- phase 1: KV + Q projection over K=256 in 4 chunks (r6 structure) ----
  for (int kt = 0; kt < 256; kt += 64) {
    __syncthreads();
#pragma unroll
    for (int i = 0; i < 7; ++i) {       // x: 208x64, 6.5 wave-rounds
      if (i < 6 || tid < 128) {
        int e = (i * 256 + tid) * 8;
        int r = e >> 6, c = e & 63;
        int xr = (r < 196) ? r : 195;   // finite dup rows for pad
        int cs = c ^ ((r & 7) << 3);
        gl_lds16(xbase + (long)xr * 256 + kt + cs, sm + e);
      }
    }
#pragma unroll
    for (int i = 0; i < 3; ++i) {       // W: 96x64 exact
      int e = (i * 256 + tid) * 8;
      int r = e >> 6, c = e & 63;
      int cs = c ^ ((r & 7) << 3);
      const u16* src = (r < 80) ? (wkvh + (long)r * 256 + kt + cs)
                                : (wqh + (long)(r - 80) * 256 + kt + cs);
      gl_lds16(src, sm + 13312 + e);
    }
    __syncthreads();
    __builtin_amdgcn_s_setprio(1);
#pragma unroll
    for (int kk = 0; kk < 64; kk += 32) {
      const int csw = (kk + hi * 8) ^ ((lo & 7) << 3);
      bf16x8 bfr[6];
#pragma unroll
      for (int nf = 0; nf < 6; ++nf)
        bfr[nf] = *(const bf16x8*)(sm + 13312 + (nf * 16 + lo) * 64 + csw);
      {
        bf16x8 aqf = *(const bf16x8*)(sm + gr * 64 + ((kk + hi * 8) ^ ((gr & 7) << 3)));
        qacc = __builtin_amdgcn_mfma_f32_16x16x32_bf16(aqf, bfr[5], qacc, 0, 0, 0);
      }
#pragma unroll
      for (int u = 0; u < 3; ++u) {
        const int mf = w + u * 4;
        bf16x8 af = *(const bf16x8*)(sm + (mf * 16 + lo) * 64 + csw);
#pragma unroll
        for (int nf = 0; nf < 5; ++nf)
          acc[u][nf] = __builtin_amdgcn_mfma_f32_16x16x32_bf16(af, bfr[nf], acc[u][nf], 0, 0, 0);
      }
      if (w) {
        bf16x8 af12 = *(const bf16x8*)(sm + (192 + lo) * 64 + csw);
        if (w == 1) {
          acc12a = __builtin_amdgcn_mfma_f32_16x16x32_bf16(af12, bfr[0], acc12a, 0, 0, 0);
          acc12b = __builtin_amdgcn_mfma_f32_16x16x32_bf16(af12, bfr[1], acc12b, 0, 0, 0);
        } else if (w == 2) {
          acc12a = __builtin_amdgcn_mfma_f32_16x16x32_bf16(af12, bfr[2], acc12a, 0, 0, 0);
          acc12b = __builtin_amdgcn_mfma_f32_16x16x32_bf16(af12, bfr[3], acc12b, 0, 0, 0);
        } else {
          acc12a = __builtin_amdgcn_mfma_f32_16x16x32_bf16(af12, bfr[4], acc12a, 0, 0, 0);
        }
      }
    }
    __builtin_amdgcn_s_setprio(0);
  }
  __syncthreads();   // staging dead; aliased K/vT/Q writes may begin

  // ---- phase-1 epilogue: RAW K/V scatter (no BN), Q with folded BN ----
#pragma unroll
  for (int u = 0; u < 3; ++u) {
    const int mf = w + u * 4;
    const int nnb = mf * 16 + hi * 4;
#pragma unroll
    for (int j = 0; j < 4; ++j)
      sm[KOFF + (nnb + j) * KS + lo] = f2bf(acc[u][0][j]);   // K raw, col=lo
#pragma unroll
    for (int nf = 1; nf < 5; ++nf) {
      const int d = nf * 16 - 16 + lo;
      uint2 pp;
      pp.x = pk2(acc[u][nf][0], acc[u][nf][1]);
      pp.y = pk2(acc[u][nf][2], acc[u][nf][3]);
      *(uint2*)(sm + d * VTS + swz(nnb, d)) = pp;            // V raw, packed b64
    }
  }
  {
    const int nnb = 192 + hi * 4;
    if (w == 1) {
#pragma unroll
      for (int j = 0; j < 4; ++j)
        sm[KOFF + (nnb + j) * KS + lo] = f2bf(acc12a[j]);
      const int d = lo;
      uint2 pp;
      pp.x = pk2(acc12b[0], acc12b[1]);
      pp.y = pk2(acc12b[2], acc12b[3]);
      *(uint2*)(sm + d * VTS + swz(nnb, d)) = pp;
    } else if (w == 2) {
      const int d0 = 16 + lo, d1 = 32 + lo;
      uint2 pa, pb;
      pa.x = pk2(acc12a[0], acc12a[1]);
      pa.y = pk2(acc12a[2], acc12a[3]);
      pb.x = pk2(acc12b[0], acc12b[1]);
      pb.y = pk2(acc12b[2], acc12b[3]);
      *(uint2*)(sm + d0 * VTS + swz(nnb, d0)) = pa;
      *(uint2*)(sm + d1 * VTS + swz(nnb, d1)) = pb;
    } else if (w == 3) {
      const int d = 48 + lo;
      uint2 pp;
      pp.x = pk2(acc12a[0], acc12a[1]);
      pp.y = pk2(acc12a[2], acc12a[3]);
      *(uint2*)(sm + d * VTS + swz(nnb, d)) = pp;
    }
  }
  {
    const float s = sqv[hh * 16 + lo], t = tqv[hh * 16 + lo];
#pragma unroll
    for (int j = 0; j < 4; ++j) {
      const int r = w * 16 + hi * 4 + j;
      sm[QOFF + r * QS + lo] = f2bf(qacc[j] * s + t);
    }
  }
  __syncthreads();

  // ---- phase 2: QK^T (scale + K-BN pre-folded into Q; per-q consts cancel) ----
  f32x4 sc[13];
  {
    bf16x8 zf = {0, 0, 0, 0, 0, 0, 0, 0};
    bf16x8 aq2 = zf;
    if (hi < 2) aq2 = *(const bf16x8*)(sm + QOFF + (w * 16 + lo) * QS + hi * 8);
#pragma unroll
    for (int t13 = 0; t13 < 13; ++t13) {
      bf16x8 bk = zf;
      if (hi < 2) bk = *(const bf16x8*)(sm + KOFF + (t13 * 16 + lo) * KS + hi * 8);
      sc[t13] = __builtin_amdgcn_mfma_f32_16x16x32_bf16(aq2, bk, z4, 0, 0, 0);
    }
  }
  __syncthreads();   // all K/Q reads done; P-half (aliasing K/Q) may be written

  // ---- softmax per C/D row; P cols 0..111 -> LDS, cols 112..207 retained in sc ----
  float rs[4];
#pragma unroll
  for (int j = 0; j < 4; ++j) {
    const int row = w * 16 + hi * 4 + j;
    const int rb = (row < 49) ? row : 0;
    float vals[13];
#pragma unroll
    for (int t = 0; t < 13; ++t) {
      const int col = t * 16 + lo;
      vals[t] = (col < 196) ? sc[t][j] + biasf[(hh * 49 + rb) * 196 + col] : -1e30f;
    }
    float mx = vals[0];
#pragma unroll
    for (int t = 1; t < 13; ++t) mx = fmaxf(mx, vals[t]);
#pragma unroll
    for (int s = 1; s < 16; s <<= 1) mx = fmaxf(mx, __shfl_xor(mx, s, 64));
    float sum = 0.f;
#pragma unroll
    for (int t = 0; t < 13; ++t) { float p = __expf(vals[t] - mx); vals[t] = p; sum += p; }
#pragma unroll
    for (int s = 1; s < 16; s <<= 1) sum += __shfl_xor(sum, s, 64);
#pragma unroll
    for (int t = 0; t < 7; ++t)
      sm[PHOFF + row * PHS + pswz(t * 16 + lo, row)] = f2bf(vals[t]);
#pragma unroll
    for (int t = 7; t < 13; ++t) sc[t][j] = vals[t];   // keep exp'd second half
    rs[j] = sum;
  }

  // ---- PV pass 0: keys 0..111 (P rows wave-private: no barriers in PV) ----
  f32x4 oacc[4];
#pragma unroll
  for (int n = 0; n < 4; ++n) oacc[n] = z4;
  const int prow = w * 16 + lo;
  const int pkey = ((lo >> 2) & 3) << 3;   // pswz key for read rows
  __builtin_amdgcn_s_setprio(1);
#pragma unroll
  for (int kt = 0; kt < 96; kt += 32) {
    bf16x8 ap = *(const bf16x8*)(sm + PHOFF + prow * PHS + ((kt + hi * 8) ^ pkey));
#pragma unroll
    for (int n = 0; n < 4; ++n) {
      bf16x8 bv = *(const bf16x8*)(sm + (n * 16 + lo) * VTS + ((kt + hi * 8) ^ ((lo & 7) << 3)));
      oacc[n] = __builtin_amdgcn_mfma_f32_16x16x32_bf16(ap, bv, oacc[n], 0, 0, 0);
    }
  }
  {  // tail keys 96..111: 16-wide, hi<2 guarded; P identity region, vT swizzled
    bf16x8 zf = {0, 0, 0, 0, 0, 0, 0, 0};
    bf16x8 ap = zf;
    if (hi < 2) ap = *(const bf16x8*)(sm + PHOFF + prow * PHS + 96 + hi * 8);
#pragma unroll
    for (int n = 0; n < 4; ++n) {
      bf16x8 bv = zf;
      if (hi < 2) bv = *(const bf16x8*)(sm + (n * 16 + lo) * VTS + ((96 + hi * 8) ^ ((lo & 7) << 3)));
      oacc[n] = __builtin_amdgcn_mfma_f32_16x16x32_bf16(ap, bv, oacc[n], 0, 0, 0);
    }
  }

  // ---- write P second half (keys 112..207 -> local cols 0..95) ----
#pragma unroll
  for (int j = 0; j < 4; ++j) {
    const int row = w * 16 + hi * 4 + j;
#pragma unroll
    for (int t = 7; t < 13; ++t)
      sm[PHOFF + row * PHS + pswz((t - 7) * 16 + lo, row)] = f2bf(sc[t][j]);
  }

  // ---- PV pass 1: keys 112..207 ----
#pragma unroll
  for (int kl = 0; kl < 96; kl += 32) {
    bf16x8 ap = *(const bf16x8*)(sm + PHOFF + prow * PHS + ((kl + hi * 8) ^ pkey));
#pragma unroll
    for (int n = 0; n < 4; ++n) {
      const int lc = 112 + kl + hi * 8;   // logical vT col; may straddle swz regions
      bf16x8 bv = *(const bf16x8*)(sm + (n * 16 + lo) * VTS + swz(lc, lo));
      oacc[n] = __builtin_amdgcn_mfma_f32_16x16x32_bf16(ap, bv, oacc[n], 0, 0, 0);
    }
  }
  __builtin_amdgcn_s_setprio(0);

  // ---- epilogue: V-BN (raw-V fold: val = O*s_d/rs + t_d), hardswish, store ----
  float svv[4], tvv[4];
#pragma unroll
  for (int n = 0; n < 4; ++n) {
    svv[n] = skv[hh * 80 + 16 + n * 16 + lo];
    tvv[n] = tkv[hh * 80 + 16 + n * 16 + lo];
  }
#pragma unroll
  for (int j = 0; j < 4; ++j) {
    const int row = w * 16 + hi * 4 + j;
    if (row < 49) {
      const float rinv = 1.f / rs[j];
      const long ob = ((long)(bb * 49 + row)) * 1024 + hh * 64 + lo;
#pragma unroll
      for (int n = 0; n < 4; ++n) {
        float val = oacc[n][j] * svv[n] * rinv + tvv[n];
        float hs = val * fminf(fmaxf(val + 3.f, 0.f), 6.f) * (1.f / 6.f);
        osw[ob + n * 16] = f2bf(hs);
      }
    }
  }
}

extern "C" void kernel_launch(void* const* d_in, const int* in_sizes, int n_in,
                              void* d_out, int out_size, void* d_ws, size_t ws_size,
                              hipStream_t stream)
{
  const float* x   = (const float*)d_in[0];
  const float* Wkv = (const float*)d_in[1];
  const float* gkv = (const float*)d_in[2];
  const float* bkv = (const float*)d_in[3];
  const float* mkv = (const float*)d_in[4];
  const float* vkv = (const float*)d_in[5];
  const float* Wq  = (const float*)d_in[6];
  const float* gq  = (const float*)d_in[7];
  const float* bq  = (const float*)d_in[8];
  const float* mq  = (const float*)d_in[9];
  const float* vq  = (const float*)d_in[10];
  const float* Wp  = (const float*)d_in[11];
  const float* gp  = (const float*)d_in[12];
  const float* bp  = (const float*)d_in[13];
  const float* mp  = (const float*)d_in[14];
  const float* vp  = (const float*)d_in[15];
  const float* ab  = (const float*)d_in[16];
  const int* bidx  = (const int*)d_in[17];

  char* ws = (char*)d_ws;
  size_t off = 0;
  auto alloc = [&](size_t bytes) -> char* {
    char* p = ws + off;
    off += (bytes + 255) & ~(size_t)255;
    return p;
  };
  u16* x_bf   = (u16*)alloc((size_t)50176 * 256 * 2);
  u16* wkv_bf = (u16*)alloc((size_t)1280 * 256 * 2);
  u16* wq_bf  = (u16*)alloc((size_t)256 * 256 * 2);
  u16* wp_bf  = (u16*)alloc((size_t)512 * 1024 * 2);
  u16* hsw    = (u16*)alloc((size_t)12544 * 1024 * 2);
  float* bias_f = (float*)alloc((size_t)153664 * 4);
  float* s_kv = (float*)alloc(1280 * 4);
  float* t_kv = (float*)alloc(1280 * 4);
  float* s_q  = (float*)alloc(256 * 4);
  float* t_q  = (float*)alloc(256 * 4);
  float* s_p  = (float*)alloc(512 * 4);
  float* t_p  = (float*)alloc(512 * 4);
  if (off > ws_size) return;  // clean failure instead of OOB writes

  prep_misc<<<4193, 256, 0, stream>>>(Wkv, Wq, Wp, gkv, bkv, mkv, vkv,
                                      gq, bq, mq, vq, gp, bp, mp, vp,
                                      ab, bidx, wkv_bf, wq_bf, wp_bf,
                                      s_kv, t_kv, s_q, t_q, s_p, t_p, bias_f);
  conv_x<<<12544, 256, 0, stream>>>(x, x_bf);
  // fused kv+q+attention: 4096 blocks = 8 XCD chunks x 512 (32 images x 16 heads)
  fused_attn<<<4096, 256, 0, stream>>>(x_bf, wkv_bf, wq_bf, s_kv, t_kv, s_q, t_q, bias_f, hsw);
  // p-proj: M=12544 (98 m-blocks), N=512 (4 n-blocks), XCD-chunked 1D grid
  gemm_bn<<<392, 256, 0, stream>>>(hsw, wp_bf, s_p, t_p, (float*)d_out, 512, 1024, 4);
}

// Round 12
// 124.424 us; speedup vs baseline: 1.0979x; 1.0979x over previous
//
#include <hip/hip_runtime.h>

typedef unsigned short u16;
typedef unsigned int u32;
typedef __attribute__((ext_vector_type(8))) short bf16x8;
typedef __attribute__((ext_vector_type(4))) float f32x4;

__device__ __forceinline__ u16 f2bf(float x) {
  union { float f; u32 u; } un; un.f = x;
  u32 r = un.u + 0x7FFFu + ((un.u >> 16) & 1u);
  return (u16)(r >> 16);
}
__device__ __forceinline__ u32 pk2(float a, float b) {
  return (u32)f2bf(a) | ((u32)f2bf(b) << 16);
}

// async global->LDS, 16B per lane; LDS dest must be wave-uniform base + lane*16
__device__ __forceinline__ void gl_lds16(const u16* gsrc, u16* ldst) {
  __builtin_amdgcn_global_load_lds(
      (const __attribute__((address_space(1))) void*)gsrc,
      (__attribute__((address_space(3))) void*)ldst,
      16, 0, 0);
}

// ---------------- prep_all: x->bf16 + weights->bf16 + BN fold + bias gather ----------------
// Single dispatch (merged conv_x + prep_misc): small ranges fill the x-convert tail.
// Q's stored scale/shift absorb: its own BN, SCALE=0.25, and K's BN scale sk_c
// (K is stored RAW; K's BN shift contributes only a per-q softmax-invariant const).
#define XCONV_N 3211264   // 50176*256/4 float4s
__global__ __launch_bounds__(256) void prep_all(
    const float* __restrict__ x,
    const float* __restrict__ Wkv, const float* __restrict__ Wq, const float* __restrict__ Wp,
    const float* __restrict__ gkv, const float* __restrict__ bkv, const float* __restrict__ mkv, const float* __restrict__ vkv,
    const float* __restrict__ gq, const float* __restrict__ bq, const float* __restrict__ mq, const float* __restrict__ vq,
    const float* __restrict__ gp, const float* __restrict__ bp, const float* __restrict__ mp, const float* __restrict__ vp,
    const float* __restrict__ ab, const int* __restrict__ bidx,
    u16* __restrict__ xbf,
    u16* __restrict__ wkvb, u16* __restrict__ wqb, u16* __restrict__ wpb,
    float* __restrict__ skv, float* __restrict__ tkv,
    float* __restrict__ sq, float* __restrict__ tq,
    float* __restrict__ sp, float* __restrict__ tp,
    float* __restrict__ biasf)
{
  int i = blockIdx.x * 256 + threadIdx.x;
  if (i < XCONV_N) {
    float4 v = ((const float4*)x)[i];
    uint2 o;
    o.x = pk2(v.x, v.y);
    o.y = pk2(v.z, v.w);
    ((uint2*)xbf)[i] = o;
    return;
  }
  i -= XCONV_N;
  if (i < 327680) { wkvb[i] = f2bf(Wkv[i]); return; }
  i -= 327680;
  if (i < 65536) { wqb[i] = f2bf(Wq[i]); return; }
  i -= 65536;
  if (i < 524288) { wpb[i] = f2bf(Wp[i]); return; }
  i -= 524288;
  if (i < 153664) { biasf[i] = ab[(i / 9604) * 196 + bidx[i % 9604]]; return; }
  i -= 153664;
  if (i < 1280) { float s = gkv[i] * rsqrtf(vkv[i] + 1e-5f); skv[i] = s; tkv[i] = bkv[i] - mkv[i] * s; return; }
  i -= 1280;
  if (i < 256) {
    int h = i >> 4, c = i & 15;
    float sk = gkv[h * 80 + c] * rsqrtf(vkv[h * 80 + c] + 1e-5f);
    float s = gq[i] * rsqrtf(vq[i] + 1e-5f);
    sq[i] = s * 0.25f * sk;
    tq[i] = (bq[i] - mq[i] * s) * 0.25f * sk;
    return;
  }
  i -= 256;
  if (i < 512) { float s = gp[i] * rsqrtf(vp[i] + 1e-5f); sp[i] = s; tp[i] = bp[i] - mp[i] * s; return; }
}

// ---------------- p-proj GEMM: out = BN(A @ W^T), f32 row-major out ----------------
__global__ __launch_bounds__(256) void gemm_bn(
    const u16* __restrict__ A, const u16* __restrict__ W,
    const float* __restrict__ sv, const float* __restrict__ tv,
    float* __restrict__ outp, int N, int K, int NBLK)
{
  __shared__ u16 As[128 * 64];
  __shared__ u16 Bs[128 * 64];
  const int tid = threadIdx.x;
  const int lane = tid & 63;
  const int wv = tid >> 6, wr = wv >> 1, wc = wv & 1;
  const int lo = lane & 15, hi = lane >> 4;

  int bid = blockIdx.x;
  int cpx = gridDim.x >> 3;
  int wg = (bid & 7) * cpx + (bid >> 3);
  const int m0 = (wg / NBLK) * 128, n0 = (wg % NBLK) * 128;

  f32x4 zero4 = {0.f, 0.f, 0.f, 0.f};
  f32x4 acc[4][4];
#pragma unroll
  for (int m = 0; m < 4; ++m)
#pragma unroll
    for (int n = 0; n < 4; ++n) acc[m][n] = zero4;

  for (int kt = 0; kt < K; kt += 64) {
    __syncthreads();
#pragma unroll
    for (int i = 0; i < 4; ++i) {
      int e = (i * 256 + tid) * 8;
      int r = e >> 6, c = e & 63;
      int cs = c ^ ((r & 7) << 3);
      gl_lds16(A + (long)(m0 + r) * K + (kt + cs), As + e);
      gl_lds16(W + (long)(n0 + r) * K + (kt + cs), Bs + e);
    }
    __syncthreads();
#pragma unroll
    for (int kk = 0; kk < 64; kk += 32) {
      bf16x8 af[4], bfr[4];
#pragma unroll
      for (int m = 0; m < 4; ++m)
        af[m] = *(const bf16x8*)(As + (wr * 64 + m * 16 + lo) * 64 + ((kk + hi * 8) ^ ((lo & 7) << 3)));
#pragma unroll
      for (int n = 0; n < 4; ++n)
        bfr[n] = *(const bf16x8*)(Bs + (wc * 64 + n * 16 + lo) * 64 + ((kk + hi * 8) ^ ((lo & 7) << 3)));
#pragma unroll
      for (int m = 0; m < 4; ++m)
#pragma unroll
        for (int n = 0; n < 4; ++n)
          acc[m][n] = __builtin_amdgcn_mfma_f32_16x16x32_bf16(af[m], bfr[n], acc[m][n], 0, 0, 0);
    }
  }
#pragma unroll
  for (int m = 0; m < 4; ++m) {
    const int row0 = m0 + wr * 64 + m * 16 + hi * 4;
#pragma unroll
    for (int n = 0; n < 4; ++n) {
      const int col = n0 + wc * 64 + n * 16 + lo;
      const float s = sv[col], t = tv[col];
#pragma unroll
      for (int j = 0; j < 4; ++j)
        outp[(long)(row0 + j) * N + col] = acc[m][n][j] * s + t;
    }
  }
}

// ---------------- fused kv-proj + q-proj + attention, one block per (b,h) ----------------
// r6 structure (verified best: 96us fused, 3 blocks/CU). LDS map (u16 offsets):
//   phase1 staging: x_s [0..13312) 208x64, W_s [13312..19456) 96x64
//   post-GEMM:      vT  [0..13312) 64x208 RAW V, K_s [13312..18304) 208x24 RAW K,
//                   Q_s [18304..19840) 64x24 (BN+folds)
//   post-QK^T:      P_s [13312..26624) 64x208 (aliases K_s/Q_s)
// Total 26624 u16 = 53248 B -> 3 blocks/CU. (4 blocks/CU crosses the per-XCD L2
// working-set cliff: r9/r11 both showed FETCH/WRITE inflation and ~108us.)
#define VTS   208
#define KOFF  13312
#define KS    24
#define QOFF  18304
#define QS    24
#define POFF  13312
#define PS    208
#define SMEM_N 26624

// range-safe XOR swizzle for stride-208 tiles: permutes within 64-col blocks,
// identity on the 16-wide tail (cols 192..207) where XOR keys would escape.
__device__ __forceinline__ int swz(int col, int rowkey) {
  return (col < 192) ? (col ^ ((rowkey & 7) << 3)) : col;
}

__global__ __launch_bounds__(256, 3) void fused_attn(
    const u16* __restrict__ xb, const u16* __restrict__ wkvb, const u16* __restrict__ wqb,
    const float* __restrict__ skv, const float* __restrict__ tkv,
    const float* __restrict__ sqv, const float* __restrict__ tqv,
    const float* __restrict__ biasf, u16* __restrict__ osw)
{
  __shared__ __align__(16) u16 sm[SMEM_N];
  const int tid = threadIdx.x;
  const int bid = blockIdx.x;
  const int wg = (bid & 7) * 512 + (bid >> 3);   // XCD chunk: 32 images per XCD
  const int bb = wg >> 4, hh = wg & 15;
  const int w = tid >> 6, lane = tid & 63, lo = lane & 15, hi = lane >> 4;

  const u16* xbase = xb + (long)bb * 196 * 256;
  const u16* wkvh = wkvb + (long)hh * 80 * 256;
  const u16* wqh  = wqb + (long)hh * 16 * 256;

  f32x4 z4 = {0.f, 0.f, 0.f, 0.f};
  // frags {w, w+4, w+8} x 5 nf; frag 12 split: w1 -> nf0,1; w2 -> nf2,3; w3 -> nf4
  f32x4 acc[3][5];
#pragma unroll
  for (int u = 0; u < 3; ++u)
#pragma unroll
    for (int nf = 0; nf < 5; ++nf) acc[u][nf] = z4;
  f32x4 acc12a = z4, acc12b = z4;
  f32x4 qacc = z4;

  // q A-frag gather row (::2 spatial subsample), clamped; in-tile LDS gather
  int qi = w * 16 + lo; if (qi > 48) qi = 48;
  const int gr = (qi / 7) * 28 + (qi % 7) * 2;

  // ---- phase 1: KV + Q projection over K=256 in 4 chunks ----
  for (int kt = 0; kt < 256; kt += 64) {
    __syncthreads();
#pragma unroll
    for (int i = 0; i < 7; ++i) {       // x: 208x64, 6.5 wave-rounds
      if (i < 6 || tid < 128) {
        int e = (i * 256 + tid) * 8;
        int r = e >> 6, c = e & 63;
        int xr = (r < 196) ? r : 195;   // finite dup rows for pad
        int cs = c ^ ((r & 7) << 3);
        gl_lds16(xbase + (long)xr * 256 + kt + cs, sm + e);
      }
    }
#pragma unroll
    for (int i = 0; i < 3; ++i) {       // W: 96x64 exact
      int e = (i * 256 + tid) * 8;
      int r = e >> 6, c = e & 63;
      int cs = c ^ ((r & 7) << 3);
      const u16* src = (r < 80) ? (wkvh + (long)r * 256 + kt + cs)
                                : (wqh + (long)(r - 80) * 256 + kt + cs);
      gl_lds16(src, sm + 13312 + e);
    }
    __syncthreads();
    __builtin_amdgcn_s_setprio(1);
#pragma unroll
    for (int kk = 0; kk < 64; kk += 32) {
      const int csw = (kk + hi * 8) ^ ((lo & 7) << 3);
      bf16x8 bfr[6];
#pragma unroll
      for (int nf = 0; nf < 6; ++nf)
        bfr[nf] = *(const bf16x8*)(sm + 13312 + (nf * 16 + lo) * 64 + csw);
      {
        bf16x8 aqf = *(const bf16x8*)(sm + gr * 64 + ((kk + hi * 8) ^ ((gr & 7) << 3)));
        qacc = __builtin_amdgcn_mfma_f32_16x16x32_bf16(aqf, bfr[5], qacc, 0, 0, 0);
      }
#pragma unroll
      for (int u = 0; u < 3; ++u) {
        const int mf = w + u * 4;
        bf16x8 af = *(const bf16x8*)(sm + (mf * 16 + lo) * 64 + csw);
#pragma unroll
        for (int nf = 0; nf < 5; ++nf)
          acc[u][nf] = __builtin_amdgcn_mfma_f32_16x16x32_bf16(af, bfr[nf], acc[u][nf], 0, 0, 0);
      }
      if (w) {
        bf16x8 af12 = *(const bf16x8*)(sm + (192 + lo) * 64 + csw);
        if (w == 1) {
          acc12a = __builtin_amdgcn_mfma_f32_16x16x32_bf16(af12, bfr[0], acc12a, 0, 0, 0);
          acc12b = __builtin_amdgcn_mfma_f32_16x16x32_bf16(af12, bfr[1], acc12b, 0, 0, 0);
        } else if (w == 2) {
          acc12a = __builtin_amdgcn_mfma_f32_16x16x32_bf16(af12, bfr[2], acc12a, 0, 0, 0);
          acc12b = __builtin_amdgcn_mfma_f32_16x16x32_bf16(af12, bfr[3], acc12b, 0, 0, 0);
        } else {
          acc12a = __builtin_amdgcn_mfma_f32_16x16x32_bf16(af12, bfr[4], acc12a, 0, 0, 0);
        }
      }
    }
    __builtin_amdgcn_s_setprio(0);
  }
  __syncthreads();   // staging dead; aliased K/vT/Q writes may begin

  // ---- phase-1 epilogue: RAW K/V scatter (no BN), Q with folded BN ----
#pragma unroll
  for (int u = 0; u < 3; ++u) {
    const int mf = w + u * 4;
    const int nnb = mf * 16 + hi * 4;
#pragma unroll
    for (int j = 0; j < 4; ++j)
      sm[KOFF + (nnb + j) * KS + lo] = f2bf(acc[u][0][j]);   // K raw, col=lo
#pragma unroll
    for (int nf = 1; nf < 5; ++nf) {
      const int d = nf * 16 - 16 + lo;
      uint2 pp;
      pp.x = pk2(acc[u][nf][0], acc[u][nf][1]);
      pp.y = pk2(acc[u][nf][2], acc[u][nf][3]);
      *(uint2*)(sm + d * VTS + swz(nnb, d)) = pp;            // V raw, packed b64
    }
  }
  {
    const int nnb = 192 + hi * 4;
    if (w == 1) {
#pragma unroll
      for (int j = 0; j < 4; ++j)
        sm[KOFF + (nnb + j) * KS + lo] = f2bf(acc12a[j]);
      const int d = lo;
      uint2 pp;
      pp.x = pk2(acc12b[0], acc12b[1]);
      pp.y = pk2(acc12b[2], acc12b[3]);
      *(uint2*)(sm + d * VTS + swz(nnb, d)) = pp;
    } else if (w == 2) {
      const int d0 = 16 + lo, d1 = 32 + lo;
      uint2 pa, pb;
      pa.x = pk2(acc12a[0], acc12a[1]);
      pa.y = pk2(acc12a[2], acc12a[3]);
      pb.x = pk2(acc12b[0], acc12b[1]);
      pb.y = pk2(acc12b[2], acc12b[3]);
      *(uint2*)(sm + d0 * VTS + swz(nnb, d0)) = pa;
      *(uint2*)(sm + d1 * VTS + swz(nnb, d1)) = pb;
    } else if (w == 3) {
      const int d = 48 + lo;
      uint2 pp;
      pp.x = pk2(acc12a[0], acc12a[1]);
      pp.y = pk2(acc12a[2], acc12a[3]);
      *(uint2*)(sm + d * VTS + swz(nnb, d)) = pp;
    }
  }
  {
    const float s = sqv[hh * 16 + lo], t = tqv[hh * 16 + lo];
#pragma unroll
    for (int j = 0; j < 4; ++j) {
      const int r = w * 16 + hi * 4 + j;
      sm[QOFF + r * QS + lo] = f2bf(qacc[j] * s + t);
    }
  }
  __syncthreads();

  // ---- phase 2: QK^T (scale + K-BN pre-folded into Q; per-q consts cancel) ----
  f32x4 sc[13];
  {
    bf16x8 zf = {0, 0, 0, 0, 0, 0, 0, 0};
    bf16x8 aq2 = zf;
    if (hi < 2) aq2 = *(const bf16x8*)(sm + QOFF + (w * 16 + lo) * QS + hi * 8);
#pragma unroll
    for (int t13 = 0; t13 < 13; ++t13) {
      bf16x8 bk = zf;
      if (hi < 2) bk = *(const bf16x8*)(sm + KOFF + (t13 * 16 + lo) * KS + hi * 8);
      sc[t13] = __builtin_amdgcn_mfma_f32_16x16x32_bf16(aq2, bk, z4, 0, 0, 0);
    }
  }
  __syncthreads();   // all K/Q reads done; P (aliasing K/Q) may be written

  // ---- softmax per C/D row; unnormalized P -> LDS (cols 0..207 all covered) ----
  float rs[4];
#pragma unroll
  for (int j = 0; j < 4; ++j) {
    const int row = w * 16 + hi * 4 + j;
    const int rb = (row < 49) ? row : 0;
    float vals[13];
#pragma unroll
    for (int t = 0; t < 13; ++t) {
      const int col = t * 16 + lo;
      vals[t] = (col < 196) ? sc[t][j] + biasf[(hh * 49 + rb) * 196 + col] : -1e30f;
    }
    float mx = vals[0];
#pragma unroll
    for (int t = 1; t < 13; ++t) mx = fmaxf(mx, vals[t]);
#pragma unroll
    for (int s = 1; s < 16; s <<= 1) mx = fmaxf(mx, __shfl_xor(mx, s, 64));
    float sum = 0.f;
#pragma unroll
    for (int t = 0; t < 13; ++t) { float p = __expf(vals[t] - mx); vals[t] = p; sum += p; }
#pragma unroll
    for (int s = 1; s < 16; s <<= 1) sum += __shfl_xor(sum, s, 64);
#pragma unroll
    for (int t = 0; t < 13; ++t) sm[POFF + row * PS + swz(t * 16 + lo, row)] = f2bf(vals[t]);
    rs[j] = sum;
  }

  // ---- PV: O(64x64) = P(64x208) @ vT-rows; P rows private per wave (no barrier) ----
  f32x4 oacc[4];
#pragma unroll
  for (int n = 0; n < 4; ++n) oacc[n] = z4;
  __builtin_amdgcn_s_setprio(1);
#pragma unroll
  for (int kt = 0; kt < 192; kt += 32) {
    bf16x8 ap = *(const bf16x8*)(sm + POFF + (w * 16 + lo) * PS + ((kt + hi * 8) ^ ((lo & 7) << 3)));
#pragma unroll
    for (int n = 0; n < 4; ++n) {
      bf16x8 bv = *(const bf16x8*)(sm + (n * 16 + lo) * VTS + ((kt + hi * 8) ^ ((lo & 7) << 3)));
      oacc[n] = __builtin_amdgcn_mfma_f32_16x16x32_bf16(ap, bv, oacc[n], 0, 0, 0);
    }
  }
  {  // tail chunk: k = 192..207, 16-wide, hi<2 guarded, no swizzle (identity region)
    bf16x8 zf = {0, 0, 0, 0, 0, 0, 0, 0};
    bf16x8 ap = zf;
    if (hi < 2) ap = *(const bf16x8*)(sm + POFF + (w * 16 + lo) * PS + 192 + hi * 8);
#pragma unroll
    for (int n = 0; n < 4; ++n) {
      bf16x8 bv = zf;
      if (hi < 2) bv = *(const bf16x8*)(sm + (n * 16 + lo) * VTS + 192 + hi * 8);
      oacc[n] = __builtin_amdgcn_mfma_f32_16x16x32_bf16(ap, bv, oacc[n], 0, 0, 0);
    }
  }
  __builtin_amdgcn_s_setprio(0);

  // ---- epilogue: V-BN (raw-V fold: val = O*s_d/rs + t_d), hardswish, store ----
  float svv[4], tvv[4];
#pragma unroll
  for (int n = 0; n < 4; ++n) {
    svv[n] = skv[hh * 80 + 16 + n * 16 + lo];
    tvv[n] = tkv[hh * 80 + 16 + n * 16 + lo];
  }
#pragma unroll
  for (int j = 0; j < 4; ++j) {
    const int row = w * 16 + hi * 4 + j;
    if (row < 49) {
      const float rinv = 1.f / rs[j];
      const long ob = ((long)(bb * 49 + row)) * 1024 + hh * 64 + lo;
#pragma unroll
      for (int n = 0; n < 4; ++n) {
        float val = oacc[n][j] * svv[n] * rinv + tvv[n];
        float hs = val * fminf(fmaxf(val + 3.f, 0.f), 6.f) * (1.f / 6.f);
        osw[ob + n * 16] = f2bf(hs);
      }
    }
  }
}

extern "C" void kernel_launch(void* const* d_in, const int* in_sizes, int n_in,
                              void* d_out, int out_size, void* d_ws, size_t ws_size,
                              hipStream_t stream)
{
  const float* x   = (const float*)d_in[0];
  const float* Wkv = (const float*)d_in[1];
  const float* gkv = (const float*)d_in[2];
  const float* bkv = (const float*)d_in[3];
  const float* mkv = (const float*)d_in[4];
  const float* vkv = (const float*)d_in[5];
  const float* Wq  = (const float*)d_in[6];
  const float* gq  = (const float*)d_in[7];
  const float* bq  = (const float*)d_in[8];
  const float* mq  = (const float*)d_in[9];
  const float* vq  = (const float*)d_in[10];
  const float* Wp  = (const float*)d_in[11];
  const float* gp  = (const float*)d_in[12];
  const float* bp  = (const float*)d_in[13];
  const float* mp  = (const float*)d_in[14];
  const float* vp  = (const float*)d_in[15];
  const float* ab  = (const float*)d_in[16];
  const int* bidx  = (const int*)d_in[17];

  char* ws = (char*)d_ws;
  size_t off = 0;
  auto alloc = [&](size_t bytes) -> char* {
    char* p = ws + off;
    off += (bytes + 255) & ~(size_t)255;
    return p;
  };
  u16* x_bf   = (u16*)alloc((size_t)50176 * 256 * 2);
  u16* wkv_bf = (u16*)alloc((size_t)1280 * 256 * 2);
  u16* wq_bf  = (u16*)alloc((size_t)256 * 256 * 2);
  u16* wp_bf  = (u16*)alloc((size_t)512 * 1024 * 2);
  u16* hsw    = (u16*)alloc((size_t)12544 * 1024 * 2);
  float* bias_f = (float*)alloc((size_t)153664 * 4);
  float* s_kv = (float*)alloc(1280 * 4);
  float* t_kv = (float*)alloc(1280 * 4);
  float* s_q  = (float*)alloc(256 * 4);
  float* t_q  = (float*)alloc(256 * 4);
  float* s_p  = (float*)alloc(512 * 4);
  float* t_p  = (float*)alloc(512 * 4);
  if (off > ws_size) return;  // clean failure instead of OOB writes

  // merged conv_x + prep: (3211264 + 1073216 + 255) / 256 = 16736.25 -> 16737 blocks
  prep_all<<<16737, 256, 0, stream>>>(x, Wkv, Wq, Wp, gkv, bkv, mkv, vkv,
                                      gq, bq, mq, vq, gp, bp, mp, vp,
                                      ab, bidx, x_bf, wkv_bf, wq_bf, wp_bf,
                                      s_kv, t_kv, s_q, t_q, s_p, t_p, bias_f);
  // fused kv+q+attention: 4096 blocks = 8 XCD chunks x 512 (32 images x 16 heads)
  fused_attn<<<4096, 256, 0, stream>>>(x_bf, wkv_bf, wq_bf, s_kv, t_kv, s_q, t_q, bias_f, hsw);
  // p-proj: M=12544 (98 m-blocks), N=512 (4 n-blocks), XCD-chunked 1D grid
  gemm_bn<<<392, 256, 0, stream>>>(hsw, wp_bf, s_p, t_p, (float*)d_out, 512, 1024, 4);
}